// Round 11
// baseline (118.352 us; speedup 1.0000x reference)
//
#include <hip/hip_runtime.h>
#include <stdint.h>

// BinaryTreeLogicNet: out = sigmoid(tree_gcd(sigmoid(x @ W^T - 2)) * w_out + b_out)
// M=65536 rows, L=256 leaves.
// R11: 32x32x16 MFMA — halve per-CU instruction slots at constant FLOPs.
//   Evidence law (R1-R10): dur ~ total issued slots / CU, ~3x inefficiency,
//   pipe-independent. 32x32x16: MFMA instr 2048->1024/CU, B ds_read 2048->~1024,
//   W fully LDS-resident (128 KB, no K-tiling) -> ONE barrier, free-running
//   waves. A: proven fp32 gather + pack, 1-step prefetch.
//   Pre-kernel W image: row j=t*32+c holds W[c*8+t] (8-leaf subtree per lane)
//   with chunk-XOR swizzle pos=c_i^c -> B-frag b128 reads perfectly
//   bank-balanced (8 dwords/bank = 8-cyc floor).
//   C layout (m74/m101 verified): col=lane&31, row=(reg&3)+8*(reg>>2)+4*(lane>>5).
//   Tree: 3 register levels + 5 shfl_xor levels. 512 thr = 8 waves x 32 rows,
//   256 blocks, 1 block/CU (132 KB LDS).

#define EPS 1e-6f
#define LOG2E 1.44269504088896340736f
#define PARAM_OFF 131072            // byte offset of param table in img

typedef __attribute__((ext_vector_type(8)))  short short8;
typedef __attribute__((ext_vector_type(4)))  short short4_t;
typedef __attribute__((ext_vector_type(16))) float float16_t;

__device__ __forceinline__ float fast_sigmoid(float z) {
    float e = __builtin_amdgcn_exp2f(-z * LOG2E);
    return __builtin_amdgcn_rcpf(1.0f + e);
}

__device__ __forceinline__ short f2bf(float f) {   // fp32 -> bf16 RNE
    uint32_t u = __builtin_bit_cast(uint32_t, f);
    u += 0x7FFFu + ((u >> 16) & 1u);
    return (short)(u >> 16);
}

__device__ __forceinline__ short8 pack8(float4 a, float4 b) {
    short8 s;
    s[0] = f2bf(a.x); s[1] = f2bf(a.y); s[2] = f2bf(a.z); s[3] = f2bf(a.w);
    s[4] = f2bf(b.x); s[5] = f2bf(b.y); s[6] = f2bf(b.z); s[7] = f2bf(b.w);
    return s;
}

__device__ __forceinline__ float ggcd(float l, float r, float lam) {
    float a = fabsf(l) + EPS;
    float b = fabsf(r) + EPS;
    float mn = fminf(a, b);
    float mx = fmaxf(a, b);
    return fmaf(lam, mn - mx, mx);   // lam*mn + (1-lam)*mx
}

__device__ __forceinline__ void lds16(const void* g, void* l) {
    __builtin_amdgcn_global_load_lds(
        (const __attribute__((address_space(1))) unsigned int*)g,
        (__attribute__((address_space(3))) unsigned int*)l, 16, 0, 0);
}

// ---- pre-kernel: W -> 128 KB bf16 image + packed params in d_ws ----
// image row j (= t*32 + c) holds W[c*8 + t]; 16B chunk c_i stored at
// pos = c_i ^ (j&31).  byte a = j*512 + pos*16 + h*8.
__global__ __launch_bounds__(256)
void convert_w(const float* __restrict__ Wl, const float* __restrict__ wts,
               const float* __restrict__ bia, char* __restrict__ img) {
    int i = blockIdx.x * 256 + threadIdx.x;   // 0..16383, 8 B each
    int a   = i * 8;
    int h   = i & 1;
    int pos = (i >> 1) & 31;
    int j   = i >> 6;                         // image row 0..255
    int c_i = pos ^ (j & 31);                 // logical chunk
    int k   = c_i * 8 + h * 4;                // source k
    int src = ((j & 31) << 3) | (j >> 5);     // W row = c*8 + t
    float4 w4 = *(const float4*)&Wl[src * 256 + k];
    short4_t s4;
    s4.x = f2bf(w4.x); s4.y = f2bf(w4.y); s4.z = f2bf(w4.z); s4.w = f2bf(w4.w);
    *(short4_t*)&img[a] = s4;

    if (i < 255) {
        float4* pvg = (float4*)(img + PARAM_OFF);
        pvg[i] = make_float4(wts[2 * i], wts[2 * i + 1], fast_sigmoid(bia[i]), 0.f);
    } else if (i == 255) {
        ((float4*)(img + PARAM_OFF))[255] = make_float4(0.f, 0.f, 0.f, 0.f);
    }
}

// ---- main kernel: 512 thr = 8 waves x 32 rows; 1 block/CU; one barrier ----
__global__ __launch_bounds__(512, 2)
void btln_main(const float* __restrict__ x, const char* __restrict__ img,
               const float* __restrict__ wout, const float* __restrict__ bout,
               float* __restrict__ out) {
    __shared__ short Ws[65536];              // 128 KB W image
    __shared__ float4 pv[256];               // 4 KB packed (w0,w1,lam)

    const int tid  = threadIdx.x;
    const int lane = tid & 63;
    const int wv   = tid >> 6;               // wave 0..7
    const int c    = lane & 31;              // MFMA col-in-tile / A row
    const int hi   = lane >> 5;              // k-half

    if (tid < 256) pv[tid] = ((const float4*)(img + PARAM_OFF))[tid];

    // stage full W image: 16 passes x (512 thr x 16 B) = 128 KB, linear
    #pragma unroll
    for (int p = 0; p < 16; ++p)
        lds16(img + p * 8192 + tid * 16, (char*)Ws + p * 8192 + tid * 16);

    const int rowbase = blockIdx.x * 256 + wv * 32;
    // this lane's A elements: row rowbase+c, k = s*16 + hi*8 + [0..7]
    const float* xr = x + (size_t)(rowbase + c) * 256 + hi * 8;

    float16_t acc[8];
    #pragma unroll
    for (int t = 0; t < 8; ++t)
        acc[t] = (float16_t){0.f,0.f,0.f,0.f,0.f,0.f,0.f,0.f,
                             0.f,0.f,0.f,0.f,0.f,0.f,0.f,0.f};

    // A for kstep 0
    float4 a0 = *(const float4*)(xr);
    float4 a1 = *(const float4*)(xr + 4);

    __syncthreads();                          // the ONLY barrier (drains glds)

    const int cbase = c * 512;                // image row byte base (j = t*32+c)
    #pragma unroll 1
    for (int s = 0; s < 16; ++s) {
        float4 n0 = a0, n1 = a1;
        if (s < 15) {                         // prefetch next kstep's A
            n0 = *(const float4*)(xr + (s + 1) * 16);
            n1 = *(const float4*)(xr + (s + 1) * 16 + 4);
        }
        short8 af = pack8(a0, a1);
        const int boff = cbase + (((s * 2 + hi) ^ c) << 4);   // swizzled chunk
        #pragma unroll
        for (int t = 0; t < 8; ++t) {
            short8 bf = *(const short8*)((const char*)Ws + t * 16384 + boff);
            acc[t] = __builtin_amdgcn_mfma_f32_32x32x16_bf16(af, bf, acc[t], 0, 0, 0);
        }
        a0 = n0; a1 = n1;
    }

    // ---- epilogue ----
    // acc[t][r]: row = (r&3)+8*(r>>2)+4*hi, col = c (tile t) -> leaf = c*8+t
    // levels 1-3 in-register (8-leaf subtree per lane), params loaded once
    float4 p10 = pv[c * 4 + 0], p11 = pv[c * 4 + 1];
    float4 p12 = pv[c * 4 + 2], p13 = pv[c * 4 + 3];
    float4 p20 = pv[128 + c * 2 + 0], p21 = pv[128 + c * 2 + 1];
    float4 p3  = pv[192 + c];

    float res[16];
    #pragma unroll
    for (int r = 0; r < 16; ++r) {
        float s0 = fast_sigmoid(acc[0][r] - 2.0f);
        float s1 = fast_sigmoid(acc[1][r] - 2.0f);
        float s2 = fast_sigmoid(acc[2][r] - 2.0f);
        float s3 = fast_sigmoid(acc[3][r] - 2.0f);
        float s4 = fast_sigmoid(acc[4][r] - 2.0f);
        float s5 = fast_sigmoid(acc[5][r] - 2.0f);
        float s6 = fast_sigmoid(acc[6][r] - 2.0f);
        float s7 = fast_sigmoid(acc[7][r] - 2.0f);
        float u0 = ggcd(s0 * p10.x, s1 * p10.y, p10.z);
        float u1 = ggcd(s2 * p11.x, s3 * p11.y, p11.z);
        float u2 = ggcd(s4 * p12.x, s5 * p12.y, p12.z);
        float u3 = ggcd(s6 * p13.x, s7 * p13.y, p13.z);
        float v0 = ggcd(u0 * p20.x, u1 * p20.y, p20.z);
        float v1 = ggcd(u2 * p21.x, u3 * p21.y, p21.z);
        res[r]   = ggcd(v0 * p3.x,  v1 * p3.y,  p3.z);
    }

    // levels 4-8: butterfly across c (5 bits); all lanes converge
    const int offs[5] = {224, 240, 248, 252, 254};
    #pragma unroll
    for (int k = 0; k < 5; ++k) {
        float4 p = pv[offs[k] + (c >> (k + 1))];
        bool isLeft = ((c >> k) & 1) == 0;
        #pragma unroll
        for (int r = 0; r < 16; ++r) {
            float o = __shfl_xor(res[r], 1 << k, 64);
            float lf = isLeft ? res[r] : o;
            float rt = isLeft ? o      : res[r];
            res[r] = ggcd(lf * p.x, rt * p.y, p.z);
        }
    }

    if (c == 0) {
        const float wo = wout[0];
        const float bo = bout[0];
        #pragma unroll
        for (int r = 0; r < 16; ++r) {
            int row = (r & 3) + ((r >> 2) << 3) + (hi << 2);
            out[rowbase + row] = fast_sigmoid(fmaf(res[r], wo, bo));
        }
    }
}

extern "C" void kernel_launch(void* const* d_in, const int* in_sizes, int n_in,
                              void* d_out, int out_size, void* d_ws, size_t ws_size,
                              hipStream_t stream) {
    const float* x   = (const float*)d_in[0];
    const float* Wl  = (const float*)d_in[1];
    const float* wts = (const float*)d_in[2];
    const float* bia = (const float*)d_in[3];
    const float* wo  = (const float*)d_in[4];
    const float* bo  = (const float*)d_in[5];
    float* out = (float*)d_out;
    char* img = (char*)d_ws;                  // 128 KB W image + 4 KB params

    convert_w<<<dim3(64), dim3(256), 0, stream>>>(Wl, wts, bia, img);

    const int rows = out_size;                // 65536
    dim3 grid(rows / 256), block(512);        // 256 blocks x 8 waves, 1 block/CU
    btln_main<<<grid, block, 0, stream>>>(x, img, wo, bo, out);
}